// Round 8
// baseline (215.709 us; speedup 1.0000x reference)
//
#include <hip/hip_runtime.h>
#include <math.h>

#define Hn 512
#define Nn 32
#define Bn 8
#define Ln 4096
#define NF 4096            // complex FFT length (= 16^3)
#define NT 256             // threads per WG
#define ROWF 4097          // cplx stride per channel row in KF workspace
#define TWOPI 6.28318530717958647692f

// ---------------- packed complex type: <2 x float> lowers to v_pk_* on gfx950 ----------------
typedef float cplx __attribute__((ext_vector_type(2)));

__device__ __forceinline__ cplx cmulf(cplx a, cplx b) {
    cplx bsw = __builtin_shufflevector(b, b, 1, 0);      // (by, bx)
    cplx asw = __builtin_shufflevector(-a, a, 1, 3);     // (-ay, ay)
    return __builtin_elementwise_fma(asw, bsw, a.x * b); // (ax bx - ay by, ax by + ay bx)
}
__device__ __forceinline__ cplx cconj(cplx a) { return (cplx){a.x, -a.y}; }
__device__ __forceinline__ cplx cswap(cplx a) { return __builtin_shufflevector(a, a, 1, 0); }
__device__ __forceinline__ cplx mulI(cplx a) { return __builtin_shufflevector(-a, a, 1, 2); }    // (-ay, ax)
__device__ __forceinline__ cplx mulNegI(cplx a) { return __builtin_shufflevector(a, -a, 1, 2); } // (ay, -ax)

// LDS dword swizzle: conflict-free (<=2 lanes/bank) for stage patterns below
__device__ __forceinline__ int SW(int a) { return a ^ ((a >> 5) & 31); }
// storage position of frequency k after DIF stages stride 256, 16, 1
__device__ __forceinline__ int pos4(int k) { return ((k & 15) << 8) | (((k >> 4) & 15) << 4) | ((k >> 8) & 15); }

__device__ __forceinline__ cplx ldz(const float* ZR, const float* ZI, int a) {
    int s = SW(a);
    return (cplx){ZR[s], ZI[s]};
}
__device__ __forceinline__ void stz(float* ZR, float* ZI, int a, cplx v) {
    int s = SW(a);
    ZR[s] = v.x;
    ZI[s] = v.y;
}

// ---------------- in-register DFT-16 ----------------
template <int SGN>
__device__ __forceinline__ void dft4(cplx& a0, cplx& a1, cplx& a2, cplx& a3) {
    cplx t0 = a0 + a2, t1 = a0 - a2;
    cplx t2 = a1 + a3, t3 = a1 - a3;
    cplx it3 = (SGN < 0) ? mulNegI(t3) : mulI(t3);
    a0 = t0 + t2;
    a2 = t0 - t2;
    a1 = t1 + it3;
    a3 = t1 - it3;
}

// natural-order input; output freq r lands in x[sl(r)], sl(r)=((r&3)<<2)|(r>>2)
// ZTOP: inputs x[8..15] are known-zero (never read)
template <int SGN, bool ZTOP>
__device__ __forceinline__ void dft16(cplx* x) {
    const float C1 = 0.92387953251128675613f, S1 = 0.38268343236508977173f, R2 = 0.70710678118654752440f;
    const float sg = (SGN < 0) ? -1.f : 1.f;
    if (ZTOP) {
#pragma unroll
        for (int q = 0; q < 4; ++q) {
            cplx xa = x[q], xb = x[q + 4];
            cplx it3 = (SGN < 0) ? mulNegI(xb) : mulI(xb);
            x[q] = xa + xb;
            x[q + 8] = xa - xb;
            x[q + 4] = xa + it3;
            x[q + 12] = xa - it3;
        }
    } else {
#pragma unroll
        for (int q = 0; q < 4; ++q) dft4<SGN>(x[q], x[q + 4], x[q + 8], x[q + 12]);
    }
    const cplx w1 = {C1, sg * S1};
    const cplx w2 = {R2, sg * R2};
    const cplx w3 = {S1, sg * C1};
    const cplx w6 = {-R2, sg * R2};
    const cplx w9 = {-C1, -sg * S1};
    x[5] = cmulf(x[5], w1);
    x[9] = cmulf(x[9], w2);
    x[13] = cmulf(x[13], w3);
    x[6] = cmulf(x[6], w2);
    x[10] = (SGN < 0) ? mulNegI(x[10]) : mulI(x[10]);
    x[14] = cmulf(x[14], w6);
    x[7] = cmulf(x[7], w3);
    x[11] = cmulf(x[11], w6);
    x[15] = cmulf(x[15], w9);
#pragma unroll
    for (int a = 0; a < 4; ++a) dft4<SGN>(x[4 * a + 0], x[4 * a + 1], x[4 * a + 2], x[4 * a + 3]);
}

// middle/last LDS stage. TW: apply stage twiddle (last stage has none).
template <int SGN, bool TW>
__device__ void stage_lds(float* ZR, float* ZI, int base, int stride, float tau) {
    cplx x[16];
#pragma unroll
    for (int p = 0; p < 16; ++p) x[p] = ldz(ZR, ZI, base + stride * p);
    if (SGN < 0) {
        dft16<SGN, false>(x);
        if (TW) {
            float s, c;
            __sincosf(TWOPI * tau, &s, &c);
            cplx w1 = {c, -s};
            cplx w = w1;
            stz(ZR, ZI, base, x[0]);
#pragma unroll
            for (int r = 1; r < 16; ++r) {
                int sl = ((r & 3) << 2) | (r >> 2);
                stz(ZR, ZI, base + stride * r, cmulf(x[sl], w));
                w = cmulf(w, w1);
            }
        } else {
#pragma unroll
            for (int r = 0; r < 16; ++r) {
                int sl = ((r & 3) << 2) | (r >> 2);
                stz(ZR, ZI, base + stride * r, x[sl]);
            }
        }
    } else {
        if (TW) {
            float s, c;
            __sincosf(TWOPI * tau, &s, &c);
            cplx w1 = {c, s};
            cplx w = w1;
#pragma unroll
            for (int r = 1; r < 16; ++r) {
                x[r] = cmulf(x[r], w);
                w = cmulf(w, w1);
            }
        }
        dft16<SGN, false>(x);
#pragma unroll
        for (int n = 0; n < 16; ++n) {
            int sl = ((n & 3) << 2) | (n >> 2);
            stz(ZR, ZI, base + stride * n, x[sl]);
        }
    }
}

// forward stage A: dft16 already done by caller; apply w_4096^{j r} (running) and scatter
__device__ __forceinline__ void scatterA(float* ZR, float* ZI, int j, cplx* x) {
    float s, c;
    __sincosf(TWOPI * (float)j * (1.f / 4096.f), &s, &c);
    cplx w1 = {c, -s};
    cplx w = w1;
    stz(ZR, ZI, j, x[0]);
#pragma unroll
    for (int r = 1; r < 16; ++r) {
        int sl = ((r & 3) << 2) | (r >> 2);
        stz(ZR, ZI, j + 256 * r, cmulf(x[sl], w));
        w = cmulf(w, w1);
    }
}

// rfft untangle + kernel-multiply + irfft re-tangle for the pair (k, 4096-k), in place.
// All 0.5 factors removed (folded as 1/4 into KF scaling). w = e^{-2pi i k/8192}.
__device__ __forceinline__ void pointwise_pair(float* ZR, float* ZI, int pk, int pm,
                                               cplx w, cplx KA, cplx KB) {
    cplx Xk = ldz(ZR, ZI, pk), Xm = ldz(ZR, ZI, pm);
    cplx Xmc = cconj(Xm);
    cplx E = Xk + Xmc;
    cplx O = mulNegI(Xk - Xmc);
    cplx P = cmulf(w, O);
    cplx Vk = E + P;
    cplx Vm = cconj(E - P);
    cplx Yk = cmulf(Vk, KA);
    cplx Ym = cmulf(Vm, KB);
    cplx Ymc = cconj(Ym);
    cplx Ze = Yk + Ymc;
    cplx T = Yk - Ymc;
    cplx Zo = cmulf(cconj(w), T);
    stz(ZR, ZI, pk, Ze + mulI(Zo));           // Ze + i Zo
    stz(ZR, ZI, pm, cconj(Ze) + cswap(Zo));   // conj(Ze) + i conj(Zo)
}

// rotor step for the jj-loop: e^{-2pi i * 32/8192} = e^{-2pi i/256}
#define WSTEP ((cplx){0.99969881869620422f, -0.024541228522912288f})

// ---------------- kernel 1: gen (parked 2-pass) + FFT -> KF spectrum (merged, R5 style) ----------------
__global__ __launch_bounds__(NT, 2) void k_fftk(const float* __restrict__ log_dt,
                                                const float* __restrict__ lnA,
                                                const float* __restrict__ A_im,
                                                const float* __restrict__ B_ri,
                                                const float* __restrict__ C_ri,
                                                const float* __restrict__ D,
                                                cplx* __restrict__ KF) {
    __shared__ float ZR[NF];
    __shared__ float ZI[NF];
    __shared__ float CST[Nn][14];
    int h = blockIdx.x, j = threadIdx.x;
    if (j < Nn) {
        int n = j, idx = h * Nn + n;
        float dt = __expf(log_dt[h]);
        float are = -__expf(lnA[idx]);
        float aim = A_im[idx];
        float dre = dt * are;
        double taud = fmod((double)dt * (double)aim * 0.15915494309189533577, 1.0);
        if (taud < 0.0) taud += 1.0;
        float tau_hi = truncf((float)taud * 4096.f) * (1.f / 4096.f);
        float tau_lo = (float)(taud - (double)tau_hi);
        float s0, c0;
        __sincosf(TWOPI * (float)taud, &s0, &c0);
        float er = __expf(dre);
        cplx w = {er * c0, er * s0};                            // e^{dt A}
        float inv2 = 1.f / (are * are + aim * aim);
        cplx num = {w.x - 1.f, w.y};
        cplx disc = {(num.x * are + num.y * aim) * inv2,
                     (num.y * are - num.x * aim) * inv2};       // (e^{dtA}-1)/A
        cplx Bc = {B_ri[2 * idx], B_ri[2 * idx + 1]};
        cplx CB = cmulf(Bc, disc);
        int i1 = Hn * Nn + idx;
        cplx cA = cmulf((cplx){C_ri[2 * idx], C_ri[2 * idx + 1]}, CB);
        cA = 2.f * cA;
        cplx cC = cmulf((cplx){C_ri[2 * i1], C_ri[2 * i1 + 1]}, CB);
        cC = 2.f * cC;
        cplx cB2 = cmulf(cA, w);
        float einv = __expf(-2.f * dre);
        cplx winv = {w.x * einv, -w.y * einv};                  // w^{-1}
        cplx cD = cmulf(cC, winv);
        double t512 = fmod(512.0 * taud, 1.0);
        float e512 = __expf(512.f * dre);
        float sR, cR;
        __sincosf(TWOPI * (float)t512, &sR, &cR);
        // packed coefficient layout: acc += qv.x*P1 + qv.y*P2 (lo pass), P3/P4 (hi pass)
        CST[n][0] = cA.x;   CST[n][1] = cB2.x;                  // P1
        CST[n][2] = -cA.y;  CST[n][3] = -cB2.y;                 // P2
        CST[n][4] = cC.x;   CST[n][5] = cD.x;                   // P3
        CST[n][6] = -cC.y;  CST[n][7] = -cD.y;                  // P4
        CST[n][8] = e512 * cR; CST[n][9] = e512 * sR;           // R512 = w^{512}
        CST[n][10] = dre; CST[n][11] = tau_hi; CST[n][12] = tau_lo;
    }
    __syncthreads();
    // gen packed time-domain kernel: x[p] = (K[2l], K[2l+1]) at l = j + 256 p.
    // Two passes of 8 accumulators; pass-lo parked in this thread's own Z slots.
    {   // pass lo: p = 0..7 (causal direction)
        cplx acc[8];
#pragma unroll
        for (int p = 0; p < 8; ++p) acc[p] = (cplx){0.f, 0.f};
        float l_lo = (float)(2 * j);
        for (int n = 0; n < Nn; ++n) {
            cplx P1 = {CST[n][0], CST[n][1]};
            cplx P2 = {CST[n][2], CST[n][3]};
            cplx R = {CST[n][8], CST[n][9]};
            float dre = CST[n][10], thi = CST[n][11], tlo = CST[n][12];
            float ph = l_lo * thi;
            ph -= floorf(ph);
            ph += l_lo * tlo;
            ph -= floorf(ph);
            float s, c;
            __sincosf(TWOPI * ph, &s, &c);
            float m0 = __expf(dre * l_lo);
            cplx qv = {m0 * c, m0 * s};                          // w^{2j}
#pragma unroll
            for (int p = 0; p < 8; ++p) {
                acc[p] = __builtin_elementwise_fma(qv.xx, P1,
                         __builtin_elementwise_fma(qv.yy, P2, acc[p]));
                qv = cmulf(qv, R);
            }
        }
#pragma unroll
        for (int p = 0; p < 8; ++p) stz(ZR, ZI, j + 256 * p, acc[p]);   // park
    }
    cplx x[16];
    {   // pass hi: p = 8..15 (anticausal, reversed; decaying iteration)
        cplx acc[8];
#pragma unroll
        for (int p = 0; p < 8; ++p) acc[p] = (cplx){0.f, 0.f};
        float l_hi = (float)(511 - 2 * j);
        for (int n = 0; n < Nn; ++n) {
            cplx P3 = {CST[n][4], CST[n][5]};
            cplx P4 = {CST[n][6], CST[n][7]};
            cplx R = {CST[n][8], CST[n][9]};
            float dre = CST[n][10], thi = CST[n][11], tlo = CST[n][12];
            float ph2 = l_hi * thi;
            ph2 -= floorf(ph2);
            ph2 += l_hi * tlo;
            ph2 -= floorf(ph2);
            float s2, c2;
            __sincosf(TWOPI * ph2, &s2, &c2);
            float m1 = __expf(dre * l_hi);
            cplx r = {m1 * c2, m1 * s2};                         // w^{511-2j}
#pragma unroll
            for (int p = 7; p >= 0; --p) {
                acc[p] = __builtin_elementwise_fma(r.xx, P3,
                         __builtin_elementwise_fma(r.yy, P4, acc[p]));
                r = cmulf(r, R);
            }
        }
#pragma unroll
        for (int p = 0; p < 8; ++p) x[8 + p] = acc[p];
    }
#pragma unroll
    for (int p = 0; p < 8; ++p) x[p] = ldz(ZR, ZI, j + 256 * p);        // unpark
    dft16<-1, false>(x);
    scatterA(ZR, ZI, j, x);   // overwrites this thread's own slots only
    __syncthreads();
    stage_lds<-1, true>(ZR, ZI, ((j >> 4) << 8) | (j & 15), 16, (float)(j & 15) * (1.f / 256.f));
    __syncthreads();
    stage_lds<-1, false>(ZR, ZI, j << 4, 1, 0.f);
    __syncthreads();
    // untangle to rfft bins; permuted coalesced layout; +D; scale 1/16384 (irfft 1/4096 x pointwise 1/4)
    float Dh = D[h];
    const float inv = 1.f / 16384.f;
    const cplx dterm = {Dh * inv, 0.f};
    const cplx half_inv = {0.5f * inv, 0.5f * inv};
    cplx* row = KF + (size_t)h * ROWF;
    {
        int k0 = ((j & 7) << 8) | (j >> 3);
        float s, c;
        __sincosf(-TWOPI * (float)k0 * (1.f / 8192.f), &s, &c);
        cplx w = {c, s};
#pragma unroll
        for (int jj = 0; jj < 8; ++jj) {
            int k = k0 | (jj << 5);
            int pk = pos4(k), pm = pos4((NF - k) & (NF - 1));
            cplx Xk = ldz(ZR, ZI, pk), Xm = ldz(ZR, ZI, pm);
            cplx Xmc = cconj(Xm);
            cplx E = Xk + Xmc;                      // 2x true E
            cplx O = mulNegI(Xk - Xmc);             // 2x true O
            cplx P = cmulf(w, O);
            row[jj * 256 + j] = __builtin_elementwise_fma(E + P, half_inv, dterm);
            row[2048 + jj * 256 + j] = cconj((E - P) * half_inv) + dterm;
            w = cmulf(w, WSTEP);
        }
    }
    if (j == NT - 1) {  // bin k = 2048 (self-paired; no 0.5 folding on this bin)
        cplx Xk = ldz(ZR, ZI, pos4(2048));
        row[4096] = (cplx){(Xk.x + Dh) * inv, -Xk.y * inv};
    }
}

// ---------------- kernel 2: FFT convolution, one (batch,channel) per WG ----------------
__global__ __launch_bounds__(NT, 5) void k_conv(const float* __restrict__ u,
                                                const cplx* __restrict__ KF,
                                                float* __restrict__ y) {
    __shared__ float ZR[NF];
    __shared__ float ZI[NF];
    int wg = blockIdx.x;
    int h = wg & 511, b = wg >> 9;   // same h -> same XCD: KF row stays in XCD L2
    int j = threadIdx.x;
    const cplx* u2 = (const cplx*)(u + ((size_t)b * Hn + h) * Ln);
    // forward stage A fused with load; upper half of padded input is zero
    cplx x[16];
#pragma unroll
    for (int p = 0; p < 8; ++p) x[p] = u2[j + 256 * p];
    dft16<-1, true>(x);
    scatterA(ZR, ZI, j, x);
    __syncthreads();
    stage_lds<-1, true>(ZR, ZI, ((j >> 4) << 8) | (j & 15), 16, (float)(j & 15) * (1.f / 256.f));
    __syncthreads();
    stage_lds<-1, false>(ZR, ZI, j << 4, 1, 0.f);
    __syncthreads();
    // pointwise multiply; w rotor recurrence replaces per-jj sincos
    const cplx* row = KF + (size_t)h * ROWF;
    {
        int k0 = ((j & 7) << 8) | (j >> 3);
        float s, c;
        __sincosf(-TWOPI * (float)k0 * (1.f / 8192.f), &s, &c);
        cplx w = {c, s};
#pragma unroll
        for (int jj = 0; jj < 8; ++jj) {
            int k = k0 | (jj << 5);
            int pk = pos4(k), pm = pos4((NF - k) & (NF - 1));
            pointwise_pair(ZR, ZI, pk, pm, w, row[jj * 256 + j], row[2048 + jj * 256 + j]);
            w = cmulf(w, WSTEP);
        }
    }
    if (j == NT - 1) {
        int p2 = pos4(2048);
        pointwise_pair(ZR, ZI, p2, p2, (cplx){0.f, -1.f}, row[4096], row[4096]);
    }
    __syncthreads();
    // inverse stages
    stage_lds<1, false>(ZR, ZI, j << 4, 1, 0.f);
    __syncthreads();
    stage_lds<1, true>(ZR, ZI, ((j >> 4) << 8) | (j & 15), 16, (float)(j & 15) * (1.f / 256.f));
    __syncthreads();
    // inverse stage A' fused with store; only first half of time outputs needed
    cplx xx[16];
#pragma unroll
    for (int p = 0; p < 16; ++p) xx[p] = ldz(ZR, ZI, j + 256 * p);
    {
        float s, c;
        __sincosf(TWOPI * (float)j * (1.f / 4096.f), &s, &c);
        cplx w1 = {c, s};
        cplx w = w1;
#pragma unroll
        for (int r = 1; r < 16; ++r) {
            xx[r] = cmulf(xx[r], w);
            w = cmulf(w, w1);
        }
    }
    dft16<1, false>(xx);
    cplx* y2 = (cplx*)(y + ((size_t)b * Hn + h) * Ln);
#pragma unroll
    for (int n = 0; n < 8; ++n) {
        int sl = ((n & 3) << 2) | (n >> 2);
        y2[j + 256 * n] = xx[sl];
    }
}

extern "C" void kernel_launch(void* const* d_in, const int* in_sizes, int n_in,
                              void* d_out, int out_size, void* d_ws, size_t ws_size,
                              hipStream_t stream) {
    const float* u = (const float*)d_in[0];
    const float* log_dt = (const float*)d_in[1];
    const float* lnA = (const float*)d_in[2];
    const float* A_im = (const float*)d_in[3];
    const float* B_ri = (const float*)d_in[4];
    const float* C_ri = (const float*)d_in[5];
    const float* D = (const float*)d_in[6];
    float* y = (float*)d_out;
    cplx* KF = (cplx*)d_ws;   // Hn * ROWF cplx = ~16.78 MB

    k_fftk<<<Hn, NT, 0, stream>>>(log_dt, lnA, A_im, B_ri, C_ri, D, KF);
    k_conv<<<Bn * Hn, NT, 0, stream>>>(u, KF, y);
}